// Round 9
// baseline (272.589 us; speedup 1.0000x reference)
//
#include <hip/hip_runtime.h>

#define D_MODEL 1024
#define N_HEADS 16
#define D_KH    64
#define BATCH   4
#define SEQ     2048
#define M_TOTAL (BATCH*SEQ)   // 8192

typedef __attribute__((ext_vector_type(8))) short short8;
typedef __attribute__((ext_vector_type(4))) float f32x4;
typedef __attribute__((ext_vector_type(4))) unsigned short u16x4;
typedef __attribute__((ext_vector_type(2))) unsigned int u32x2;

__device__ __forceinline__ unsigned short f2bf(float f) {
  union { float f; unsigned u; } v; v.f = f;
  unsigned r = v.u + 0x7FFFu + ((v.u >> 16) & 1u);
  return (unsigned short)(r >> 16);
}
__device__ __forceinline__ unsigned fbits(float f) {
  union { float f; unsigned u; } v; v.f = f; return v.u;
}
// LDS swizzle for bf16 [R][64] tiles (verified r3: correct + kills the
// 16-lane column conflict). For fragment reads row&7 == l16&7 (rows step
// by 16) so the XOR folds to a per-lane constant.
__device__ __forceinline__ int sw(int row, int col) {
  return row * 64 + (col ^ ((row & 7) << 3));
}

// ---------------------------------------------------------------- cvt_all
// (unchanged from round 7 -- verified)
__global__ __launch_bounds__(256) void cvt_all(
    const float* __restrict__ Q, unsigned short* __restrict__ Qbf,
    const float* __restrict__ Wq, const float* __restrict__ Wk,
    const float* __restrict__ Wv, unsigned short* __restrict__ WT) {
  __shared__ float tile[32][33];
  const int bid = blockIdx.x;
  if (bid < 8192) {
    size_t i = (size_t)bid * 256 + threadIdx.x;
    float4 v = ((const float4*)Q)[i];
    u16x4 o;
    o[0] = f2bf(v.x); o[1] = f2bf(v.y); o[2] = f2bf(v.z); o[3] = f2bf(v.w);
    ((u16x4*)Qbf)[i] = o;
  } else {
    const int r = bid - 8192;
    const int z = r >> 10;                 // 0..2
    const int rem = r & 1023;
    const int k0 = (rem >> 5) * 32, n0 = (rem & 31) * 32;
    const float* W = (z == 0) ? Wq : (z == 1) ? Wk : Wv;
    const int tx = threadIdx.x & 31, ty = threadIdx.x >> 5;
    for (int i = 0; i < 4; ++i)
      tile[ty + i * 8][tx] = W[(size_t)(k0 + ty + i * 8) * D_MODEL + n0 + tx];
    __syncthreads();
    unsigned short* out = WT + (size_t)z * D_MODEL * D_MODEL;
    for (int i = 0; i < 4; ++i)
      out[(size_t)(n0 + ty + i * 8) * D_MODEL + k0 + tx] = f2bf(tile[tx][ty + i * 8]);
  }
}

// ---------------------------------------------------------------- gemm_qkv
// 256x256 tile, BK=64, 512 thr (8 waves 2x4), 128 KB LDS, 8-phase.
// RACE FIX vs r8: vmcnt waits are now BEFORE the phase-ending barrier
// (wait -> barrier -> read), so every wave's staged chunks are landed
// before ANY wave reads them. r8 waited at phase top with no following
// barrier -> read other waves' in-flight LDS-DMA -> NaN.
// Ledger (FIFO per tile: A0,B1,B0,A1; stages p1..p8 = B0^o, A1^o,
// A0^{e+2}, B1^{e+2}, B0^{e+2}, A1^{e+2}, A0^{o+2}, B1^{o+2}):
//   vmcnt(4) before bar2 of p4  -> forces through A1^o  -> covers p5-p8
//   vmcnt(4) before bar2 of p8  -> forces through A1^{e+2} -> covers
//     p1-p4 of the next iteration
//   prologue vmcnt(4)+barrier (12 issued - 4 left = through A1^{t0})
// WAR safety: each region's last reader consumed it via MFMA in the
// previous phase (lgkmcnt drained before that phase's bar2) -> re-stage
// one phase later is safe. Tail: dummy stages via (tile & 15), never read.
#define GQ_NT 16

#define GQ_STAGE_HALF(buf, tile, isB, half) do {                               \
    int kt_ = (tile) & 15;                                                     \
    _Pragma("unroll")                                                          \
    for (int r_ = 0; r_ < 2; ++r_) {                                           \
      int o_   = (r_ * 512 + t) * 8;          /* elem in half: 0..8191 */      \
      int row_ = (half) * 128 + (o_ >> 6);                                     \
      int col_ = (o_ & 63) ^ ((row_ & 7) << 3);  /* pre-swizzled source */     \
      const unsigned short* g_ = (isB)                                         \
          ? WT  + (size_t)(n0g + row_) * D_MODEL + kt_ * 64 + col_             \
          : Qbf + (size_t)(m0  + row_) * D_MODEL + kt_ * 64 + col_;            \
      unsigned short* l_ = ((isB) ? &smB[buf][0] : &smA[buf][0])               \
                           + (half) * 8192 + o_;   /* linear dest */           \
      __builtin_amdgcn_global_load_lds(                                        \
          (const __attribute__((address_space(1))) void*)g_,                   \
          (__attribute__((address_space(3))) void*)l_, 16, 0, 0);              \
    }                                                                          \
  } while (0)

#define GQ_PHASE(buf, ah, bh, WAIT4, stTile, stB, stHalf) do {                 \
    short8 a_[2][4], b_[2][2];                                                 \
    _Pragma("unroll")                                                          \
    for (int kh_ = 0; kh_ < 2; ++kh_) {                                        \
      _Pragma("unroll")                                                        \
      for (int mi_ = 0; mi_ < 4; ++mi_) {                                      \
        int row_ = (ah) * 128 + wr * 64 + mi_ * 16 + l16;                      \
        a_[kh_][mi_] = *(const short8*)&smA[buf][sw(row_, kh_ * 32 + quad * 8)]; \
      }                                                                        \
      _Pragma("unroll")                                                        \
      for (int ni_ = 0; ni_ < 2; ++ni_) {                                      \
        int row_ = (bh) * 128 + wc * 32 + ni_ * 16 + l16;                      \
        b_[kh_][ni_] = *(const short8*)&smB[buf][sw(row_, kh_ * 32 + quad * 8)]; \
      }                                                                        \
    }                                                                          \
    GQ_STAGE_HALF(((stTile) & 1), stTile, stB, stHalf);                        \
    __builtin_amdgcn_s_barrier();                                              \
    asm volatile("" ::: "memory");                                             \
    __builtin_amdgcn_s_setprio(1);                                             \
    _Pragma("unroll")                                                          \
    for (int mi_ = 0; mi_ < 4; ++mi_) {                                        \
      _Pragma("unroll")                                                        \
      for (int ni_ = 0; ni_ < 2; ++ni_) {                                      \
        acc[(ah) * 4 + mi_][(bh) * 2 + ni_] =                                  \
            __builtin_amdgcn_mfma_f32_16x16x32_bf16(                           \
                a_[0][mi_], b_[0][ni_], acc[(ah) * 4 + mi_][(bh) * 2 + ni_],   \
                0, 0, 0);                                                      \
        acc[(ah) * 4 + mi_][(bh) * 2 + ni_] =                                  \
            __builtin_amdgcn_mfma_f32_16x16x32_bf16(                           \
                a_[1][mi_], b_[1][ni_], acc[(ah) * 4 + mi_][(bh) * 2 + ni_],   \
                0, 0, 0);                                                      \
      }                                                                        \
    }                                                                          \
    __builtin_amdgcn_s_setprio(0);                                             \
    if (WAIT4) asm volatile("s_waitcnt vmcnt(4)" ::: "memory");                \
    __builtin_amdgcn_s_barrier();                                              \
    asm volatile("" ::: "memory");                                             \
  } while (0)

__global__ __launch_bounds__(512, 2) void gemm_qkv(
    const unsigned short* __restrict__ Qbf,
    const unsigned short* __restrict__ WT,
    const float* __restrict__ bq_p, const float* __restrict__ bk_p,
    const float* __restrict__ bv_p,
    float* __restrict__ out_qa,
    unsigned short* __restrict__ kbf,
    unsigned short* __restrict__ vt) {
  const int f   = blockIdx.x;                 // 0..383
  const int swz = (f & 7) * 48 + (f >> 3);    // XCD-bijective (384%8==0)
  const int mm  = swz / 12;                   // 0..31  (m-outer)
  const int nn  = swz % 12;                   // 0..11
  const int m0  = mm * 256;
  const int n0g = nn * 256;                   // global col in [0,3072)
  const int z   = n0g >> 10;                  // block-uniform (1024%256==0)
  const int n0  = n0g & 1023;

  __shared__ unsigned short smA[2][256 * 64];  // 32 KB each buffer
  __shared__ unsigned short smB[2][256 * 64];  // total 128 KB

  const int t    = threadIdx.x;
  const int lane = t & 63;
  const int w    = t >> 6;              // 0..7
  const int quad = lane >> 4;
  const int l16  = lane & 15;
  const int wr   = w >> 2;              // 0..1 (row-half within quadrant)
  const int wc   = w & 3;               // 0..3 (32-col slice)

  f32x4 acc[8][4];
  #pragma unroll
  for (int i = 0; i < 8; ++i)
    #pragma unroll
    for (int j = 0; j < 4; ++j) acc[i][j] = (f32x4){0.f, 0.f, 0.f, 0.f};

  // prologue: 6 halves in steady-state tag order, then WAIT -> BARRIER.
  // vmcnt(4): 12 issued - 4 left in flight = forced through A1(t0).
  GQ_STAGE_HALF(0, 0, 0, 0);   // A0 t0
  GQ_STAGE_HALF(0, 0, 1, 1);   // B1 t0
  GQ_STAGE_HALF(0, 0, 1, 0);   // B0 t0
  GQ_STAGE_HALF(0, 0, 0, 1);   // A1 t0
  GQ_STAGE_HALF(1, 1, 0, 0);   // A0 t1
  GQ_STAGE_HALF(1, 1, 1, 1);   // B1 t1
  asm volatile("s_waitcnt vmcnt(4)" ::: "memory");
  __builtin_amdgcn_s_barrier();
  asm volatile("" ::: "memory");

  for (int i = 0; i < GQ_NT / 2; ++i) {
    const int e = 2 * i;          // buf0
    const int o = 2 * i + 1;      // buf1
    //        buf ah bh W4  stageTile stB stH
    GQ_PHASE(0,  0, 0, 0,  o,        1,  0);   // read A0e,B0e | stage B0^o
    GQ_PHASE(0,  0, 1, 0,  o,        0,  1);   // read A0e,B1e | stage A1^o
    GQ_PHASE(0,  1, 1, 0,  e + 2,    0,  0);   // read A1e,B1e | stage A0^{e+2}
    GQ_PHASE(0,  1, 0, 1,  e + 2,    1,  1);   // read A1e,B0e | stage B1^{e+2} | vmcnt(4)->A1^o
    GQ_PHASE(1,  0, 0, 0,  e + 2,    1,  0);   // read A0o,B0o | stage B0^{e+2}
    GQ_PHASE(1,  0, 1, 0,  e + 2,    0,  1);   // read A0o,B1o | stage A1^{e+2}
    GQ_PHASE(1,  1, 1, 0,  o + 2,    0,  0);   // read A1o,B1o | stage A0^{o+2}
    GQ_PHASE(1,  1, 0, 1,  o + 2,    1,  1);   // read A1o,B0o | stage B1^{o+2} | vmcnt(4)->A1^{e+2}
  }
  asm volatile("s_waitcnt vmcnt(0)" ::: "memory");   // drain dummy stages

  const float* bias = (z == 0) ? bq_p : (z == 1) ? bk_p : bv_p;
  if (z == 2) {
    #pragma unroll
    for (int bh = 0; bh < 2; ++bh) {
      #pragma unroll
      for (int ni = 0; ni < 2; ++ni) {
        int n = n0 + bh * 128 + wc * 32 + ni * 16 + l16;
        float bval = bias[n];
        int h = n >> 6, d = n & 63;
        #pragma unroll
        for (int ah = 0; ah < 2; ++ah) {
          #pragma unroll
          for (int mi = 0; mi < 4; ++mi) {
            int m = m0 + ah * 128 + wr * 64 + mi * 16 + quad * 4;
            int b = m >> 11, s = m & 2047;
            u16x4 oo;
            #pragma unroll
            for (int j = 0; j < 4; ++j)
              oo[j] = f2bf(acc[ah * 4 + mi][bh * 2 + ni][j] + bval);
            *(u16x4*)&vt[(size_t)((b * 16 + h) * 64 + d) * SEQ + s] = oo;
          }
        }
      }
    }
  } else {
    #pragma unroll
    for (int bh = 0; bh < 2; ++bh) {
      #pragma unroll
      for (int ni = 0; ni < 2; ++ni) {
        int n = n0 + bh * 128 + wc * 32 + ni * 16 + l16;
        float bval = bias[n];
        #pragma unroll
        for (int ah = 0; ah < 2; ++ah) {
          #pragma unroll
          for (int mi = 0; mi < 4; ++mi) {
            int mbase = m0 + ah * 128 + wr * 64 + mi * 16 + quad * 4;
            #pragma unroll
            for (int j = 0; j < 4; ++j) {
              float v = acc[ah * 4 + mi][bh * 2 + ni][j] + bval;
              size_t idx = (size_t)(mbase + j) * D_MODEL + n;
              if (z == 0) out_qa[idx] = v;
              else        kbf[idx] = f2bf(v);
            }
          }
        }
      }
    }
  }
}

// ---------------------------------------------------------------- attn
// BYTE-EXACT round 3 (verified 80.6 us steady; restored+confirmed r7).
#define PST 72   // LDS row stride (elements)
#define QBLK 128

__global__ __launch_bounds__(256, 4) void attn(
    const float* __restrict__ qa,            // [8192,1024] fp32
    const unsigned short* __restrict__ kbf,  // [8192,1024] bf16
    const unsigned short* __restrict__ vt,   // [(bh)*64+d][2048] bf16 (V^T)
    const int* __restrict__ length,
    float* __restrict__ ctx) {               // [8192,1024] fp32
  const int flat = blockIdx.y * 16 + blockIdx.x;          // 0..1023
  const int low = flat & 3;
  const int mid = (flat >> 2) & 15;
  const int hi  = flat >> 6;                              // 0..15
  const int b  = (low + mid + (mid >> 2) + hi + (hi >> 2)) & 3;
  const int h  = mid;
  const int qt = hi;                                      // 128-q tile index
  const int bh = b * 16 + h;
  const int len = length[b];

  const int t    = threadIdx.x;
  const int lane = t & 63;
  const int w    = t >> 6;              // 0..3
  const int quad = lane >> 4;
  const int l16  = lane & 15;
  const int r8   = t >> 3;              // 0..31
  const int c8   = (t & 7) * 8;         // 0,8,..,56

  __shared__ unsigned short sQ[QBLK * PST];  // [q][d] pre-scaled; reused as sP
  __shared__ unsigned short sK[64 * PST];    // [k][d]
  __shared__ unsigned short sVT[64 * PST];   // [d][k]
  unsigned short* const sP = sQ;             // [q][k] alias

  const float SCL = 0.125f * 1.44269504f;   // 1/sqrt(64) * log2(e)

  for (int half = 0; half < 4; ++half) {
    int r = r8 + half * 32;
    const float* src = qa + (size_t)(b * SEQ + qt * QBLK + r) * D_MODEL + h * D_KH + c8;
    float4 v0 = *(const float4*)src;
    float4 v1 = *(const float4*)(src + 4);
    short8 o;
    o[0] = (short)f2bf(v0.x * SCL); o[1] = (short)f2bf(v0.y * SCL);
    o[2] = (short)f2bf(v0.z * SCL); o[3] = (short)f2bf(v0.w * SCL);
    o[4] = (short)f2bf(v1.x * SCL); o[5] = (short)f2bf(v1.y * SCL);
    o[6] = (short)f2bf(v1.z * SCL); o[7] = (short)f2bf(v1.w * SCL);
    *(short8*)&sQ[r * PST + c8] = o;
  }
  __syncthreads();

  const int qr0 = w * 16 + l16;
  const int qr1 = 64 + qr0;
  short8 qf00 = *(const short8*)&sQ[qr0 * PST + quad * 8];
  short8 qf01 = *(const short8*)&sQ[qr0 * PST + 32 + quad * 8];
  short8 qf10 = *(const short8*)&sQ[qr1 * PST + quad * 8];
  short8 qf11 = *(const short8*)&sQ[qr1 * PST + 32 + quad * 8];

  f32x4 acc0[4], acc1[4];
  for (int i = 0; i < 4; ++i) {
    acc0[i] = (f32x4){0.f, 0.f, 0.f, 0.f};
    acc1[i] = (f32x4){0.f, 0.f, 0.f, 0.f};
  }
  float den0 = 0.f, den1 = 0.f;

  const unsigned short* kbase_p = kbf + (size_t)b * SEQ * D_MODEL + h * D_KH;
  const unsigned short* vbase_p = vt + (size_t)bh * 64 * SEQ;

  const int nkt = (len + 63) >> 6;

  short8 rk[2], rv[2];
  for (int half = 0; half < 2; ++half) {
    int r = r8 + half * 32;
    rk[half] = *(const short8*)(kbase_p + (size_t)r * D_MODEL + c8);
    rv[half] = *(const short8*)(vbase_p + (size_t)r * SEQ + c8);
  }

  for (int kt = 0; kt < nkt; ++kt) {
    __syncthreads();   // prev-iter readers done (covers qf reads on kt=0)
    for (int half = 0; half < 2; ++half) {
      int r = r8 + half * 32;
      *(short8*)&sK[r * PST + c8]  = rk[half];
      *(short8*)&sVT[r * PST + c8] = rv[half];
    }
    __syncthreads();   // staging visible

    if (kt + 1 < nkt) {
      for (int half = 0; half < 2; ++half) {
        int r = r8 + half * 32;
        rk[half] = *(const short8*)(kbase_p + (size_t)((kt + 1) * 64 + r) * D_MODEL + c8);
        rv[half] = *(const short8*)(vbase_p + (size_t)r * SEQ + (kt + 1) * 64 + c8);
      }
    }

    const bool full = ((kt + 1) << 6) <= len;   // block-uniform

    for (int n = 0; n < 4; ++n) {
      short8 kf0 = *(const short8*)&sK[(n * 16 + l16) * PST + quad * 8];
      short8 kf1 = *(const short8*)&sK[(n * 16 + l16) * PST + 32 + quad * 8];
      f32x4 s0 = (f32x4){0.f, 0.f, 0.f, 0.f};
      s0 = __builtin_amdgcn_mfma_f32_16x16x32_bf16(kf0, qf00, s0, 0, 0, 0);
      s0 = __builtin_amdgcn_mfma_f32_16x16x32_bf16(kf1, qf01, s0, 0, 0, 0);
      f32x4 s1 = (f32x4){0.f, 0.f, 0.f, 0.f};
      s1 = __builtin_amdgcn_mfma_f32_16x16x32_bf16(kf0, qf10, s1, 0, 0, 0);
      s1 = __builtin_amdgcn_mfma_f32_16x16x32_bf16(kf1, qf11, s1, 0, 0, 0);

      float e0, e1, e2, e3, f0, f1, f2, f3;
      if (full) {
        e0 = exp2f(s0[0]); e1 = exp2f(s0[1]); e2 = exp2f(s0[2]); e3 = exp2f(s0[3]);
        f0 = exp2f(s1[0]); f1 = exp2f(s1[1]); f2 = exp2f(s1[2]); f3 = exp2f(s1[3]);
      } else {
        int kb = kt * 64 + n * 16 + quad * 4;
        e0 = (kb + 0 < len) ? exp2f(s0[0]) : 0.f;
        e1 = (kb + 1 < len) ? exp2f(s0[1]) : 0.f;
        e2 = (kb + 2 < len) ? exp2f(s0[2]) : 0.f;
        e3 = (kb + 3 < len) ? exp2f(s0[3]) : 0.f;
        f0 = (kb + 0 < len) ? exp2f(s1[0]) : 0.f;
        f1 = (kb + 1 < len) ? exp2f(s1[1]) : 0.f;
        f2 = (kb + 2 < len) ? exp2f(s1[2]) : 0.f;
        f3 = (kb + 3 < len) ? exp2f(s1[3]) : 0.f;
      }
      den0 += (e0 + e1) + (e2 + e3);
      den1 += (f0 + f1) + (f2 + f3);
      u32x2 pk;
      pk[0] = __builtin_amdgcn_perm(fbits(e1), fbits(e0), 0x07060302);
      pk[1] = __builtin_amdgcn_perm(fbits(e3), fbits(e2), 0x07060302);
      *(u32x2*)&sP[qr0 * PST + n * 16 + quad * 4] = pk;
      u32x2 pk1;
      pk1[0] = __builtin_amdgcn_perm(fbits(f1), fbits(f0), 0x07060302);
      pk1[1] = __builtin_amdgcn_perm(fbits(f3), fbits(f2), 0x07060302);
      *(u32x2*)&sP[qr1 * PST + n * 16 + quad * 4] = pk1;
    }
    // sP rows are per-wave -> no barrier before PV

    short8 pf00 = *(const short8*)&sP[qr0 * PST + quad * 8];
    short8 pf01 = *(const short8*)&sP[qr0 * PST + 32 + quad * 8];
    short8 pf10 = *(const short8*)&sP[qr1 * PST + quad * 8];
    short8 pf11 = *(const short8*)&sP[qr1 * PST + 32 + quad * 8];
    for (int n2 = 0; n2 < 4; ++n2) {
      short8 vf0 = *(const short8*)&sVT[(n2 * 16 + l16) * PST + quad * 8];
      short8 vf1 = *(const short8*)&sVT[(n2 * 16 + l16) * PST + 32 + quad * 8];
      acc0[n2] = __builtin_amdgcn_mfma_f32_16x16x32_bf16(vf0, pf00, acc0[n2], 0, 0, 0);
      acc0[n2] = __builtin_amdgcn_mfma_f32_16x16x32_bf16(vf1, pf01, acc0[n2], 0, 0, 0);
      acc1[n2] = __builtin_amdgcn_mfma_f32_16x16x32_bf16(vf0, pf10, acc1[n2], 0, 0, 0);
      acc1[n2] = __builtin_amdgcn_mfma_f32_16x16x32_bf16(vf1, pf11, acc1[n2], 0, 0, 0);
    }
  }

  den0 += __shfl_xor(den0, 16, 64);
  den0 += __shfl_xor(den0, 32, 64);
  den1 += __shfl_xor(den1, 16, 64);
  den1 += __shfl_xor(den1, 32, 64);
  float inv0 = 1.f / (den0 + 1e-8f);
  float inv1 = 1.f / (den1 + 1e-8f);

  {
    int q0 = qt * QBLK + w * 16 + l16;
    float* dst0 = ctx + (size_t)(b * SEQ + q0) * D_MODEL + h * D_KH;
    float* dst1 = dst0 + (size_t)64 * D_MODEL;   // q0 + 64
    for (int n2 = 0; n2 < 4; ++n2) {
      f32x4 o0 = acc0[n2];
      f32x4 o1 = acc1[n2];
      *(float4*)(dst0 + n2 * 16 + quad * 4) =
          make_float4(o0[0] * inv0, o0[1] * inv0, o0[2] * inv0, o0[3] * inv0);
      *(float4*)(dst1 + n2 * 16 + quad * 4) =
          make_float4(o1[0] * inv1, o1[1] * inv1, o1[2] * inv1, o1[3] * inv1);
    }
  }
}

// ---------------------------------------------------------------- launch
extern "C" void kernel_launch(void* const* d_in, const int* in_sizes, int n_in,
                              void* d_out, int out_size, void* d_ws, size_t ws_size,
                              hipStream_t stream) {
  const float* Q      = (const float*)d_in[0];
  const int*   length = (const int*)d_in[1];
  const float* Wq     = (const float*)d_in[2];
  const float* bq     = (const float*)d_in[3];
  const float* Wk     = (const float*)d_in[4];
  const float* bk     = (const float*)d_in[5];
  const float* Wv     = (const float*)d_in[6];
  const float* bv     = (const float*)d_in[7];

  float* out_ctx = (float*)d_out;                         // [8192,1024]
  float* out_qa  = out_ctx + (size_t)M_TOTAL * D_MODEL;   // [8192,1024]

  char* ws = (char*)d_ws;
  unsigned short* Qbf = (unsigned short*)ws;                              // 16 MB
  unsigned short* WT  = (unsigned short*)(ws + (size_t)16 * 1024 * 1024); //  6 MB
  unsigned short* Kbf = (unsigned short*)(ws + (size_t)22 * 1024 * 1024); // 16 MB
  unsigned short* Vt  = (unsigned short*)(ws + (size_t)38 * 1024 * 1024); // 16 MB

  hipLaunchKernelGGL(cvt_all, dim3(8192 + 3072), dim3(256), 0, stream,
                     Q, Qbf, Wq, Wk, Wv, WT);
  hipLaunchKernelGGL(gemm_qkv, dim3(384), dim3(512), 0, stream,
                     Qbf, WT, bq, bk, bv, out_qa, Kbf, Vt);
  hipLaunchKernelGGL(attn, dim3(SEQ / QBLK, BATCH * N_HEADS), dim3(256), 0, stream,
                     out_qa, Kbf, Vt, length, out_ctx);
}